// Round 4
// baseline (353.180 us; speedup 1.0000x reference)
//
#include <hip/hip_runtime.h>

// Problem constants (from reference)
#define BATCH 2
#define HH 512
#define WW 512
#define NIN 64
#define NOUT 64
#define N_NZ 131072
#define N_MASK 131072
#define NPIX (BATCH * HH * WW)   // 524288
#define PPW 64                   // points per wave in conv kernel
#define MAX_ALIVE N_MASK         // alive pixels <= number of mask points

// d_ws layout (compact path):
//   [0,256)                      int counter
//   [256, 256+2MB)               float mask[NPIX]
//   [.., +2MB)                   int   slot[NPIX]
//   [.., +32MB)                  float compact[MAX_ALIVE*NOUT]
#define WS_MASK_OFF   256
#define WS_SLOT_OFF   (WS_MASK_OFF + (size_t)NPIX * 4)
#define WS_CMP_OFF    (WS_SLOT_OFF + (size_t)NPIX * 4)
#define WS_NEED       (WS_CMP_OFF + (size_t)MAX_ALIVE * NOUT * 4)

// ---------------------------------------------------------------------------
// Mask scatter:  mask[b,y,x] += mask_values[n]
// ---------------------------------------------------------------------------
__global__ void mask_scatter_kernel(const float* __restrict__ mv,
                                    const int* __restrict__ midx,
                                    float* __restrict__ mask) {
    int n = blockIdx.x * blockDim.x + threadIdx.x;
    if (n < N_MASK) {
        int b = midx[n * 3 + 0];
        int y = midx[n * 3 + 1];
        int x = midx[n * 3 + 2];
        atomicAdd(&mask[(b * HH + y) * WW + x], mv[n]);
    }
}

// ---------------------------------------------------------------------------
// Slot assignment: alive pixels get a compact slot id, dead pixels -1.
// ---------------------------------------------------------------------------
__global__ void build_slot_kernel(const float* __restrict__ mask,
                                  int* __restrict__ slot,
                                  int* __restrict__ counter) {
    int p = blockIdx.x * blockDim.x + threadIdx.x;
    if (p < NPIX) {
        slot[p] = (mask[p] != 0.0f) ? atomicAdd(counter, 1) : -1;
    }
}

// ---------------------------------------------------------------------------
// Conv scatter v2: register-cached kernel slice, lane-parallel destination
// probe + ballot, compacted alive loop, atomics into the compact buffer.
// One wave per (tap, tile-of-64-points).
//   probe phase: lane j handles point p0+j (coalesced idx loads, one
//                scattered slot gather, one ballot) — no serial probe chain.
//   alive phase: iterate set bits; values row via wave-uniform s_loads,
//                64 FMA into kreg, one coalesced atomicAdd per contribution.
// ---------------------------------------------------------------------------
__global__ __launch_bounds__(64) void conv_scatter2_kernel(
        const float* __restrict__ values,   // (N_NZ, NIN)
        const float* __restrict__ kern,     // (3,3,NIN,NOUT)
        const int* __restrict__ idx,        // (N_NZ,3) int32
        const int* __restrict__ slot,       // (NPIX,) slot id or -1
        float* __restrict__ compact) {      // (MAX_ALIVE, NOUT) zeroed
    const int bid  = blockIdx.x;
    const int tap  = bid % 9;               // 9 taps of a tile run adjacent
    const int tile = bid / 9;               // -> values rows L2-hot
    const int lane = threadIdx.x;
    const int ky = tap / 3;
    const int kx = tap % 3;

    // This tap's 64x64 kernel slice -> 64 VGPRs (lane = output channel).
    float kreg[NIN];
    const float* kp = kern + (size_t)tap * NIN * NOUT + lane;
#pragma unroll
    for (int i = 0; i < NIN; ++i) kreg[i] = kp[(size_t)i * NOUT];

    // Lane-parallel probe of 64 points' destinations.
    const int p0 = tile * PPW;
    const int p  = p0 + lane;
    const int b = idx[p * 3 + 0];
    const int y = idx[p * 3 + 1];
    const int x = idx[p * 3 + 2];
    const int sy = min(max(y + ky - 1, 0), HH - 1);
    const int sx = min(max(x + kx - 1, 0), WW - 1);
    const int pix = (b * HH + sy) * WW + sx;
    const int s = slot[pix];

    unsigned long long alive = __ballot(s >= 0);
    while (alive) {
        const int j = __ffsll((long long)alive) - 1;  // scalar (ballot-derived)
        alive &= alive - 1;
        const int sj = __shfl(s, j);                  // slot of point j
        const float* vp = values + (size_t)(p0 + j) * NIN;  // uniform -> s_load
        float acc = 0.0f;
#pragma unroll
        for (int i = 0; i < NIN; ++i) acc = fmaf(vp[i], kreg[i], acc);
        atomicAdd(&compact[(size_t)sj * NOUT + lane], acc);
    }
}

// ---------------------------------------------------------------------------
// Streaming finalize: writes EVERY output element exactly once.
//   dead pixel  -> 0
//   alive pixel -> (compact[slot] + m*bias) * m
// 16 threads per pixel, float4 each. No d_out memset needed.
// ---------------------------------------------------------------------------
__global__ void finalize2_kernel(float* __restrict__ out,
                                 const float* __restrict__ mask,
                                 const int* __restrict__ slot,
                                 const float* __restrict__ compact,
                                 const float* __restrict__ bias) {
    const int t = blockIdx.x * blockDim.x + threadIdx.x;
    const int p = t >> 4;
    const int c4 = (t & 15) * 4;
    if (p >= NPIX) return;
    float4* o = reinterpret_cast<float4*>(out + (size_t)p * NOUT + c4);
    const int s = slot[p];
    if (s < 0) {
        *o = make_float4(0.f, 0.f, 0.f, 0.f);
        return;
    }
    const float m = mask[p];
    const float4 bb = *reinterpret_cast<const float4*>(bias + c4);
    float4 v = *reinterpret_cast<const float4*>(compact + (size_t)s * NOUT + c4);
    v.x = (v.x + m * bb.x) * m;
    v.y = (v.y + m * bb.y) * m;
    v.z = (v.z + m * bb.z) * m;
    v.w = (v.w + m * bb.w) * m;
    *o = v;
}

// ======================= Fallback path (R3, proven) ========================
__global__ __launch_bounds__(64) void conv_scatter_kernel(
        const float* __restrict__ values,
        const float* __restrict__ kern,
        const int* __restrict__ idx,
        const float* __restrict__ mask,
        float* __restrict__ dense) {
    const int bid  = blockIdx.x;
    const int tap  = bid % 9;
    const int tile = bid / 9;
    const int lane = threadIdx.x;
    const int ky = tap / 3;
    const int kx = tap % 3;
    float kreg[NIN];
    const float* kp = kern + (size_t)tap * NIN * NOUT + lane;
#pragma unroll
    for (int i = 0; i < NIN; ++i) kreg[i] = kp[(size_t)i * NOUT];
    const int p0 = tile * PPW;
    for (int pp = 0; pp < PPW; ++pp) {
        const int p = p0 + pp;
        const int b = idx[p * 3 + 0];
        const int y = idx[p * 3 + 1];
        const int x = idx[p * 3 + 2];
        const int sy = min(max(y + ky - 1, 0), HH - 1);
        const int sx = min(max(x + kx - 1, 0), WW - 1);
        const size_t pix = ((size_t)b * HH + sy) * WW + sx;
        if (mask[pix] != 0.0f) {
            const float* vp = values + (size_t)p * NIN;
            float acc = 0.0f;
#pragma unroll
            for (int i = 0; i < NIN; ++i) acc = fmaf(vp[i], kreg[i], acc);
            atomicAdd(&dense[pix * NOUT + lane], acc);
        }
    }
}

__global__ void finalize_kernel(float* __restrict__ out,
                                const float* __restrict__ mask,
                                const float* __restrict__ bias) {
    const int t = blockIdx.x * blockDim.x + threadIdx.x;
    const int p = t >> 4;
    const int c4 = (t & 15) * 4;
    if (p >= NPIX) return;
    const float m = mask[p];
    if (m == 0.0f) return;
    float4* o = reinterpret_cast<float4*>(out + (size_t)p * NOUT + c4);
    const float4 bb = *reinterpret_cast<const float4*>(bias + c4);
    float4 v = *o;
    v.x = (v.x + m * bb.x) * m;
    v.y = (v.y + m * bb.y) * m;
    v.z = (v.z + m * bb.z) * m;
    v.w = (v.w + m * bb.w) * m;
    *o = v;
}

extern "C" void kernel_launch(void* const* d_in, const int* in_sizes, int n_in,
                              void* d_out, int out_size, void* d_ws, size_t ws_size,
                              hipStream_t stream) {
    const float* values      = (const float*)d_in[0];
    const float* kern        = (const float*)d_in[1];
    const float* bias        = (const float*)d_in[2];
    const float* mask_values = (const float*)d_in[3];
    const int*   indices     = (const int*)d_in[4];
    const int*   mask_idx    = (const int*)d_in[5];
    float* out = (float*)d_out;

    if (ws_size >= WS_NEED) {
        // ---- compact path ----
        char* ws = (char*)d_ws;
        int*   counter = (int*)ws;
        float* mask    = (float*)(ws + WS_MASK_OFF);
        int*   slot    = (int*)(ws + WS_SLOT_OFF);
        float* compact = (float*)(ws + WS_CMP_OFF);

        // Zero counter+mask+slot+compact in one shot (~36 MB).
        hipMemsetAsync(ws, 0, WS_NEED, stream);

        mask_scatter_kernel<<<(N_MASK + 255) / 256, 256, 0, stream>>>(
            mask_values, mask_idx, mask);
        build_slot_kernel<<<(NPIX + 255) / 256, 256, 0, stream>>>(
            mask, slot, counter);

        const int nblocks = 9 * (N_NZ / PPW);
        conv_scatter2_kernel<<<nblocks, 64, 0, stream>>>(
            values, kern, indices, slot, compact);

        const int total = NPIX * (NOUT / 4);
        finalize2_kernel<<<(total + 255) / 256, 256, 0, stream>>>(
            out, mask, slot, compact, bias);
    } else {
        // ---- fallback: R3 structure ----
        float* mask = (float*)d_ws;
        hipMemsetAsync(out, 0, (size_t)out_size * sizeof(float), stream);
        hipMemsetAsync(mask, 0, (size_t)NPIX * sizeof(float), stream);
        mask_scatter_kernel<<<(N_MASK + 255) / 256, 256, 0, stream>>>(
            mask_values, mask_idx, mask);
        const int nblocks = 9 * (N_NZ / PPW);
        conv_scatter_kernel<<<nblocks, 64, 0, stream>>>(
            values, kern, indices, mask, out);
        const int total = NPIX * (NOUT / 4);
        finalize_kernel<<<(total + 255) / 256, 256, 0, stream>>>(out, mask, bias);
    }
}

// Round 5
// 267.212 us; speedup vs baseline: 1.3217x; 1.3217x over previous
//
#include <hip/hip_runtime.h>

// Problem constants (from reference)
#define BATCH 2
#define HH 512
#define WW 512
#define NIN 64
#define NOUT 64
#define N_NZ 131072
#define N_MASK 131072
#define NPIX (BATCH * HH * WW)   // 524288
#define PPW 64                   // points per wave in conv kernel
#define MAX_ALIVE N_MASK         // alive pixels <= number of mask points

// d_ws layout (compact path):
//   [0,256)            int counter
//   [256, +2MB)        float mask[NPIX]
//   [.., +2MB)         int   slot[NPIX]
//   [.., +32MB)        float compact[MAX_ALIVE*NOUT]
#define WS_MASK_OFF   256
#define WS_SLOT_OFF   (WS_MASK_OFF + (size_t)NPIX * 4)
#define WS_CMP_OFF    (WS_SLOT_OFF + (size_t)NPIX * 4)
#define WS_NEED       (WS_CMP_OFF + (size_t)MAX_ALIVE * NOUT * 4)

// ---------------------------------------------------------------------------
// Mask scatter:  mask[b,y,x] += mask_values[n]
// ---------------------------------------------------------------------------
__global__ void mask_scatter_kernel(const float* __restrict__ mv,
                                    const int* __restrict__ midx,
                                    float* __restrict__ mask) {
    int n = blockIdx.x * blockDim.x + threadIdx.x;
    if (n < N_MASK) {
        int b = midx[n * 3 + 0];
        int y = midx[n * 3 + 1];
        int x = midx[n * 3 + 2];
        atomicAdd(&mask[(b * HH + y) * WW + x], mv[n]);
    }
}

// ---------------------------------------------------------------------------
// Slot assignment v2: block-aggregated scan, ONE counter atomic per block
// (R4's per-thread counter atomic serialized 8192 waves on one address).
// 256 threads/block, each handles 4 pixels via float4. 512 blocks total.
// ---------------------------------------------------------------------------
__global__ __launch_bounds__(256) void build_slot2_kernel(
        const float* __restrict__ mask,
        int* __restrict__ slot,
        int* __restrict__ counter) {
    const int tid = threadIdx.x;
    const int gid = blockIdx.x * 256 + tid;     // over NPIX/4 groups
    const float4 m = reinterpret_cast<const float4*>(mask)[gid];
    const int c0 = (m.x != 0.f) + (m.y != 0.f) + (m.z != 0.f) + (m.w != 0.f);

    // inclusive scan within wave
    const int lane = tid & 63;
    const int wv = tid >> 6;
    int pre = c0;
#pragma unroll
    for (int d = 1; d < 64; d <<= 1) {
        int t = __shfl_up(pre, d);
        if (lane >= d) pre += t;
    }

    __shared__ int wsum[4];
    __shared__ int wbase[4];
    __shared__ int blockbase;
    if (lane == 63) wsum[wv] = pre;
    __syncthreads();
    if (tid == 0) {
        int s = 0;
#pragma unroll
        for (int w = 0; w < 4; ++w) { wbase[w] = s; s += wsum[w]; }
        blockbase = atomicAdd(counter, s);      // ONE atomic per block
    }
    __syncthreads();

    int s0 = blockbase + wbase[wv] + (pre - c0);  // my exclusive prefix
    int4 sv;
    sv.x = (m.x != 0.f) ? s0++ : -1;
    sv.y = (m.y != 0.f) ? s0++ : -1;
    sv.z = (m.z != 0.f) ? s0++ : -1;
    sv.w = (m.w != 0.f) ? s0++ : -1;
    reinterpret_cast<int4*>(slot)[gid] = sv;
}

// ---------------------------------------------------------------------------
// Conv scatter v2: one wave per (tap, 64-point tile). lane = output channel.
// __launch_bounds__(64, 2): VGPR cap 256 so the 64-float kernel slice stays
// REGISTER-resident (R3/R4 compiled to VGPR=36 — the compiler had sunk the
// kreg loads back into the loop, re-reading 16 KB per point from cache).
// Probe phase is lane-parallel (coalesced idx, one slot gather, one ballot);
// alive loop does s_load-broadcast values row -> v_fmac with register kreg.
// ---------------------------------------------------------------------------
__global__ __launch_bounds__(64, 2) void conv_scatter2_kernel(
        const float* __restrict__ values,   // (N_NZ, NIN)
        const float* __restrict__ kern,     // (3,3,NIN,NOUT)
        const int* __restrict__ idx,        // (N_NZ,3) int32
        const int* __restrict__ slot,       // (NPIX,) slot id or -1
        float* __restrict__ compact) {      // (MAX_ALIVE, NOUT) zeroed
    const int bid  = blockIdx.x;
    const int tap  = bid % 9;               // 9 taps of a tile run adjacent
    const int tile = bid / 9;               // -> values rows L2-hot
    const int lane = threadIdx.x;
    const int ky = tap / 3;
    const int kx = tap % 3;

    // This tap's 64x64 kernel slice -> 64 VGPRs (lane = output channel).
    float kreg[NIN];
    const float* kp = kern + (size_t)tap * NIN * NOUT + lane;
#pragma unroll
    for (int i = 0; i < NIN; ++i) kreg[i] = kp[(size_t)i * NOUT];

    // Lane-parallel probe of 64 points' destinations.
    const int p0 = tile * PPW;
    const int p  = p0 + lane;
    const int b = idx[p * 3 + 0];
    const int y = idx[p * 3 + 1];
    const int x = idx[p * 3 + 2];
    const int sy = min(max(y + ky - 1, 0), HH - 1);
    const int sx = min(max(x + kx - 1, 0), WW - 1);
    const int pix = (b * HH + sy) * WW + sx;
    const int s = slot[pix];

    unsigned long long alive = __ballot(s >= 0);
    while (alive) {
        const int j = __ffsll((long long)alive) - 1;  // uniform (ballot)
        alive &= alive - 1;
        const int sj = __shfl(s, j);                  // slot of point j
        const float* vp = values + (size_t)(p0 + j) * NIN;  // uniform->s_load
        float acc = 0.0f;
#pragma unroll
        for (int i = 0; i < NIN; ++i) acc = fmaf(vp[i], kreg[i], acc);
        atomicAdd(&compact[(size_t)sj * NOUT + lane], acc);
    }
}

// ---------------------------------------------------------------------------
// Streaming finalize: writes EVERY output element exactly once.
//   dead pixel  -> 0 ; alive -> (compact[slot] + m*bias) * m
// 16 threads per pixel, float4 each. No d_out memset needed.
// ---------------------------------------------------------------------------
__global__ void finalize2_kernel(float* __restrict__ out,
                                 const float* __restrict__ mask,
                                 const int* __restrict__ slot,
                                 const float* __restrict__ compact,
                                 const float* __restrict__ bias) {
    const int t = blockIdx.x * blockDim.x + threadIdx.x;
    const int p = t >> 4;
    const int c4 = (t & 15) * 4;
    if (p >= NPIX) return;
    float4* o = reinterpret_cast<float4*>(out + (size_t)p * NOUT + c4);
    const int s = slot[p];
    if (s < 0) {
        *o = make_float4(0.f, 0.f, 0.f, 0.f);
        return;
    }
    const float m = mask[p];
    const float4 bb = *reinterpret_cast<const float4*>(bias + c4);
    float4 v = *reinterpret_cast<const float4*>(compact + (size_t)s * NOUT + c4);
    v.x = (v.x + m * bb.x) * m;
    v.y = (v.y + m * bb.y) * m;
    v.z = (v.z + m * bb.z) * m;
    v.w = (v.w + m * bb.w) * m;
    *o = v;
}

// ======================= Fallback path (R3, proven) ========================
__global__ __launch_bounds__(64, 2) void conv_scatter_kernel(
        const float* __restrict__ values,
        const float* __restrict__ kern,
        const int* __restrict__ idx,
        const float* __restrict__ mask,
        float* __restrict__ dense) {
    const int bid  = blockIdx.x;
    const int tap  = bid % 9;
    const int tile = bid / 9;
    const int lane = threadIdx.x;
    const int ky = tap / 3;
    const int kx = tap % 3;
    float kreg[NIN];
    const float* kp = kern + (size_t)tap * NIN * NOUT + lane;
#pragma unroll
    for (int i = 0; i < NIN; ++i) kreg[i] = kp[(size_t)i * NOUT];
    const int p0 = tile * PPW;
    for (int pp = 0; pp < PPW; ++pp) {
        const int p = p0 + pp;
        const int b = idx[p * 3 + 0];
        const int y = idx[p * 3 + 1];
        const int x = idx[p * 3 + 2];
        const int sy = min(max(y + ky - 1, 0), HH - 1);
        const int sx = min(max(x + kx - 1, 0), WW - 1);
        const size_t pix = ((size_t)b * HH + sy) * WW + sx;
        if (mask[pix] != 0.0f) {
            const float* vp = values + (size_t)p * NIN;
            float acc = 0.0f;
#pragma unroll
            for (int i = 0; i < NIN; ++i) acc = fmaf(vp[i], kreg[i], acc);
            atomicAdd(&dense[pix * NOUT + lane], acc);
        }
    }
}

__global__ void finalize_kernel(float* __restrict__ out,
                                const float* __restrict__ mask,
                                const float* __restrict__ bias) {
    const int t = blockIdx.x * blockDim.x + threadIdx.x;
    const int p = t >> 4;
    const int c4 = (t & 15) * 4;
    if (p >= NPIX) return;
    const float m = mask[p];
    if (m == 0.0f) return;
    float4* o = reinterpret_cast<float4*>(out + (size_t)p * NOUT + c4);
    const float4 bb = *reinterpret_cast<const float4*>(bias + c4);
    float4 v = *o;
    v.x = (v.x + m * bb.x) * m;
    v.y = (v.y + m * bb.y) * m;
    v.z = (v.z + m * bb.z) * m;
    v.w = (v.w + m * bb.w) * m;
    *o = v;
}

extern "C" void kernel_launch(void* const* d_in, const int* in_sizes, int n_in,
                              void* d_out, int out_size, void* d_ws, size_t ws_size,
                              hipStream_t stream) {
    const float* values      = (const float*)d_in[0];
    const float* kern        = (const float*)d_in[1];
    const float* bias        = (const float*)d_in[2];
    const float* mask_values = (const float*)d_in[3];
    const int*   indices     = (const int*)d_in[4];
    const int*   mask_idx    = (const int*)d_in[5];
    float* out = (float*)d_out;

    if (ws_size >= WS_NEED) {
        // ---- compact path ----
        char* ws = (char*)d_ws;
        int*   counter = (int*)ws;
        float* mask    = (float*)(ws + WS_MASK_OFF);
        int*   slot    = (int*)(ws + WS_SLOT_OFF);
        float* compact = (float*)(ws + WS_CMP_OFF);

        hipMemsetAsync(ws, 0, WS_NEED, stream);  // counter+mask+slot+compact

        mask_scatter_kernel<<<(N_MASK + 255) / 256, 256, 0, stream>>>(
            mask_values, mask_idx, mask);
        build_slot2_kernel<<<NPIX / 4 / 256, 256, 0, stream>>>(
            mask, slot, counter);

        const int nblocks = 9 * (N_NZ / PPW);
        conv_scatter2_kernel<<<nblocks, 64, 0, stream>>>(
            values, kern, indices, slot, compact);

        const int total = NPIX * (NOUT / 4);
        finalize2_kernel<<<(total + 255) / 256, 256, 0, stream>>>(
            out, mask, slot, compact, bias);
    } else {
        // ---- fallback: R3 structure ----
        float* mask = (float*)d_ws;
        hipMemsetAsync(out, 0, (size_t)out_size * sizeof(float), stream);
        hipMemsetAsync(mask, 0, (size_t)NPIX * sizeof(float), stream);
        mask_scatter_kernel<<<(N_MASK + 255) / 256, 256, 0, stream>>>(
            mask_values, mask_idx, mask);
        const int nblocks = 9 * (N_NZ / PPW);
        conv_scatter_kernel<<<nblocks, 64, 0, stream>>>(
            values, kern, indices, mask, out);
        const int total = NPIX * (NOUT / 4);
        finalize_kernel<<<(total + 255) / 256, 256, 0, stream>>>(out, mask, bias);
    }
}

// Round 6
// 266.058 us; speedup vs baseline: 1.3275x; 1.0043x over previous
//
#include <hip/hip_runtime.h>

// Problem constants (from reference)
#define BATCH 2
#define HH 512
#define WW 512
#define NIN 64
#define NOUT 64
#define N_NZ 131072
#define N_MASK 131072
#define NPIX (BATCH * HH * WW)   // 524288
#define PPW 64                   // points per wave in conv kernel
#define MAX_ALIVE N_MASK         // alive pixels <= number of mask points

// d_ws layout (compact path):
//   [0,256)            int counter
//   [256, +2MB)        float mask[NPIX]
//   [.., +2MB)         int   slot[NPIX]
//   [.., +32MB)        float compact[MAX_ALIVE*NOUT]
#define WS_MASK_OFF   256
#define WS_SLOT_OFF   (WS_MASK_OFF + (size_t)NPIX * 4)
#define WS_CMP_OFF    (WS_SLOT_OFF + (size_t)NPIX * 4)
#define WS_NEED       (WS_CMP_OFF + (size_t)MAX_ALIVE * NOUT * 4)

// ---------------------------------------------------------------------------
// Mask scatter:  mask[b,y,x] += mask_values[n]
// ---------------------------------------------------------------------------
__global__ void mask_scatter_kernel(const float* __restrict__ mv,
                                    const int* __restrict__ midx,
                                    float* __restrict__ mask) {
    int n = blockIdx.x * blockDim.x + threadIdx.x;
    if (n < N_MASK) {
        int b = midx[n * 3 + 0];
        int y = midx[n * 3 + 1];
        int x = midx[n * 3 + 2];
        atomicAdd(&mask[(b * HH + y) * WW + x], mv[n]);
    }
}

// ---------------------------------------------------------------------------
// Slot assignment: block-aggregated scan, ONE counter atomic per block.
// ---------------------------------------------------------------------------
__global__ __launch_bounds__(256) void build_slot2_kernel(
        const float* __restrict__ mask,
        int* __restrict__ slot,
        int* __restrict__ counter) {
    const int tid = threadIdx.x;
    const int gid = blockIdx.x * 256 + tid;     // over NPIX/4 groups
    const float4 m = reinterpret_cast<const float4*>(mask)[gid];
    const int c0 = (m.x != 0.f) + (m.y != 0.f) + (m.z != 0.f) + (m.w != 0.f);

    const int lane = tid & 63;
    const int wv = tid >> 6;
    int pre = c0;
#pragma unroll
    for (int d = 1; d < 64; d <<= 1) {
        int t = __shfl_up(pre, d);
        if (lane >= d) pre += t;
    }

    __shared__ int wsum[4];
    __shared__ int wbase[4];
    __shared__ int blockbase;
    if (lane == 63) wsum[wv] = pre;
    __syncthreads();
    if (tid == 0) {
        int s = 0;
#pragma unroll
        for (int w = 0; w < 4; ++w) { wbase[w] = s; s += wsum[w]; }
        blockbase = atomicAdd(counter, s);      // ONE atomic per block
    }
    __syncthreads();

    int s0 = blockbase + wbase[wv] + (pre - c0);  // exclusive prefix
    int4 sv;
    sv.x = (m.x != 0.f) ? s0++ : -1;
    sv.y = (m.y != 0.f) ? s0++ : -1;
    sv.z = (m.z != 0.f) ? s0++ : -1;
    sv.w = (m.w != 0.f) ? s0++ : -1;
    reinterpret_cast<int4*>(slot)[gid] = sv;
}

// ---------------------------------------------------------------------------
// Conv scatter v3: register-PINNED kernel slice.
// R5 evidence: VGPR_Count=36 — LLVM rematerialized the loop-invariant kern
// loads and re-read 16 KB/wave per alive point from L1/L2 (~4.3 GB). The
// empty asm below makes each kreg[i] opaque: the compiler cannot re-derive
// it from memory, so 64 VGPRs hold the slice and the alive loop is pure
// v_fmac_f32 (s_load-broadcast values row x register weights).
// ---------------------------------------------------------------------------
__global__ __launch_bounds__(64, 2) void conv_scatter3_kernel(
        const float* __restrict__ values,   // (N_NZ, NIN)
        const float* __restrict__ kern,     // (3,3,NIN,NOUT)
        const int* __restrict__ idx,        // (N_NZ,3) int32
        const int* __restrict__ slot,       // (NPIX,) slot id or -1
        float* __restrict__ compact) {      // (MAX_ALIVE, NOUT) zeroed
    const int bid  = blockIdx.x;
    const int tap  = bid % 9;               // 9 taps of a tile run adjacent
    const int tile = bid / 9;               // -> values rows L2-hot
    const int lane = threadIdx.x;
    const int ky = tap / 3;
    const int kx = tap % 3;

    // This tap's 64x64 kernel slice -> 64 VGPRs (lane = output channel).
    float kreg[NIN];
    const float* kp = kern + (size_t)tap * NIN * NOUT + lane;
#pragma unroll
    for (int i = 0; i < NIN; ++i) kreg[i] = kp[(size_t)i * NOUT];
    // Pin: forbid rematerialization (the whole point of this round).
#pragma unroll
    for (int i = 0; i < NIN; ++i) asm volatile("" : "+v"(kreg[i]));

    // Lane-parallel probe of 64 points' destinations.
    const int p0 = tile * PPW;
    const int p  = p0 + lane;
    const int b = idx[p * 3 + 0];
    const int y = idx[p * 3 + 1];
    const int x = idx[p * 3 + 2];
    const int sy = min(max(y + ky - 1, 0), HH - 1);
    const int sx = min(max(x + kx - 1, 0), WW - 1);
    const int pix = (b * HH + sy) * WW + sx;
    const int s = slot[pix];

    unsigned long long alive = __ballot(s >= 0);
    while (alive) {
        const int j = __ffsll((long long)alive) - 1;  // uniform (ballot)
        alive &= alive - 1;
        const int sj = __shfl(s, j);                  // slot of point j
        const float* vp = values + (size_t)(p0 + j) * NIN;  // uniform->s_load
        float acc = 0.0f;
#pragma unroll
        for (int i = 0; i < NIN; ++i) acc = fmaf(vp[i], kreg[i], acc);
        atomicAdd(&compact[(size_t)sj * NOUT + lane], acc);
    }
}

// ---------------------------------------------------------------------------
// Streaming finalize: writes EVERY output element exactly once.
//   dead pixel  -> 0 ; alive -> (compact[slot] + m*bias) * m
// ---------------------------------------------------------------------------
__global__ void finalize2_kernel(float* __restrict__ out,
                                 const float* __restrict__ mask,
                                 const int* __restrict__ slot,
                                 const float* __restrict__ compact,
                                 const float* __restrict__ bias) {
    const int t = blockIdx.x * blockDim.x + threadIdx.x;
    const int p = t >> 4;
    const int c4 = (t & 15) * 4;
    if (p >= NPIX) return;
    float4* o = reinterpret_cast<float4*>(out + (size_t)p * NOUT + c4);
    const int s = slot[p];
    if (s < 0) {
        *o = make_float4(0.f, 0.f, 0.f, 0.f);
        return;
    }
    const float m = mask[p];
    const float4 bb = *reinterpret_cast<const float4*>(bias + c4);
    float4 v = *reinterpret_cast<const float4*>(compact + (size_t)s * NOUT + c4);
    v.x = (v.x + m * bb.x) * m;
    v.y = (v.y + m * bb.y) * m;
    v.z = (v.z + m * bb.z) * m;
    v.w = (v.w + m * bb.w) * m;
    *o = v;
}

// ======================= Fallback path (R3, proven) ========================
__global__ __launch_bounds__(64, 2) void conv_scatter_kernel(
        const float* __restrict__ values,
        const float* __restrict__ kern,
        const int* __restrict__ idx,
        const float* __restrict__ mask,
        float* __restrict__ dense) {
    const int bid  = blockIdx.x;
    const int tap  = bid % 9;
    const int tile = bid / 9;
    const int lane = threadIdx.x;
    const int ky = tap / 3;
    const int kx = tap % 3;
    float kreg[NIN];
    const float* kp = kern + (size_t)tap * NIN * NOUT + lane;
#pragma unroll
    for (int i = 0; i < NIN; ++i) kreg[i] = kp[(size_t)i * NOUT];
#pragma unroll
    for (int i = 0; i < NIN; ++i) asm volatile("" : "+v"(kreg[i]));
    const int p0 = tile * PPW;
    for (int pp = 0; pp < PPW; ++pp) {
        const int p = p0 + pp;
        const int b = idx[p * 3 + 0];
        const int y = idx[p * 3 + 1];
        const int x = idx[p * 3 + 2];
        const int sy = min(max(y + ky - 1, 0), HH - 1);
        const int sx = min(max(x + kx - 1, 0), WW - 1);
        const size_t pix = ((size_t)b * HH + sy) * WW + sx;
        if (mask[pix] != 0.0f) {
            const float* vp = values + (size_t)p * NIN;
            float acc = 0.0f;
#pragma unroll
            for (int i = 0; i < NIN; ++i) acc = fmaf(vp[i], kreg[i], acc);
            atomicAdd(&dense[pix * NOUT + lane], acc);
        }
    }
}

__global__ void finalize_kernel(float* __restrict__ out,
                                const float* __restrict__ mask,
                                const float* __restrict__ bias) {
    const int t = blockIdx.x * blockDim.x + threadIdx.x;
    const int p = t >> 4;
    const int c4 = (t & 15) * 4;
    if (p >= NPIX) return;
    const float m = mask[p];
    if (m == 0.0f) return;
    float4* o = reinterpret_cast<float4*>(out + (size_t)p * NOUT + c4);
    const float4 bb = *reinterpret_cast<const float4*>(bias + c4);
    float4 v = *o;
    v.x = (v.x + m * bb.x) * m;
    v.y = (v.y + m * bb.y) * m;
    v.z = (v.z + m * bb.z) * m;
    v.w = (v.w + m * bb.w) * m;
    *o = v;
}

extern "C" void kernel_launch(void* const* d_in, const int* in_sizes, int n_in,
                              void* d_out, int out_size, void* d_ws, size_t ws_size,
                              hipStream_t stream) {
    const float* values      = (const float*)d_in[0];
    const float* kern        = (const float*)d_in[1];
    const float* bias        = (const float*)d_in[2];
    const float* mask_values = (const float*)d_in[3];
    const int*   indices     = (const int*)d_in[4];
    const int*   mask_idx    = (const int*)d_in[5];
    float* out = (float*)d_out;

    if (ws_size >= WS_NEED) {
        // ---- compact path ----
        char* ws = (char*)d_ws;
        int*   counter = (int*)ws;
        float* mask    = (float*)(ws + WS_MASK_OFF);
        int*   slot    = (int*)(ws + WS_SLOT_OFF);
        float* compact = (float*)(ws + WS_CMP_OFF);

        hipMemsetAsync(ws, 0, WS_NEED, stream);  // counter+mask+slot+compact

        mask_scatter_kernel<<<(N_MASK + 255) / 256, 256, 0, stream>>>(
            mask_values, mask_idx, mask);
        build_slot2_kernel<<<NPIX / 4 / 256, 256, 0, stream>>>(
            mask, slot, counter);

        const int nblocks = 9 * (N_NZ / PPW);
        conv_scatter3_kernel<<<nblocks, 64, 0, stream>>>(
            values, kern, indices, slot, compact);

        const int total = NPIX * (NOUT / 4);
        finalize2_kernel<<<(total + 255) / 256, 256, 0, stream>>>(
            out, mask, slot, compact, bias);
    } else {
        // ---- fallback: R3 structure ----
        float* mask = (float*)d_ws;
        hipMemsetAsync(out, 0, (size_t)out_size * sizeof(float), stream);
        hipMemsetAsync(mask, 0, (size_t)NPIX * sizeof(float), stream);
        mask_scatter_kernel<<<(N_MASK + 255) / 256, 256, 0, stream>>>(
            mask_values, mask_idx, mask);
        const int nblocks = 9 * (N_NZ / PPW);
        conv_scatter_kernel<<<nblocks, 64, 0, stream>>>(
            values, kern, indices, mask, out);
        const int total = NPIX * (NOUT / 4);
        finalize_kernel<<<(total + 255) / 256, 256, 0, stream>>>(out, mask, bias);
    }
}